// Round 6
// baseline (306.290 us; speedup 1.0000x reference)
//
#include <hip/hip_runtime.h>
#include <math.h>

// Problem shape (fixed by the bench's setup_inputs)
#define NS 16384
#define ND 2048
#define NC 1000
#define NCPAD 1024

typedef _Float16 f16x8 __attribute__((ext_vector_type(8)));
typedef _Float16 f16x4 __attribute__((ext_vector_type(4)));
typedef __fp16   h16x2 __attribute__((ext_vector_type(2)));
typedef float f32x4  __attribute__((ext_vector_type(4)));

// Candidate window: must exceed 2*E where E bounds |approx - exact| per score.
// A is RTZ-converted in-GEMM (r0-validated), B is RN: E <= 10-sigma of
// sum-of-2048 f16-product errors (~0.7 with RTZ A) + f16 store round (<=0.11)
// => 2E ~ 1.6.  Delta = 2.5 keeps margin.
#define DELTA 2.5f

// Fast path: mhi 4MB + sc 32MB = 36 MB (xh intermediate ELIMINATED this round)
#define WS_FAST 37748736ull

__device__ __forceinline__ void gl_lds16_h(const _Float16* g, _Float16* l) {
    __builtin_amdgcn_global_load_lds(
        (const __attribute__((address_space(1))) unsigned int*)g,
        (__attribute__((address_space(3))) unsigned int*)l, 16, 0, 0);
}

// fp32x8 -> f16x8 (RTZ pack) — used by the fused A-conversion staging
__device__ __forceinline__ f16x8 cvt8(const f32x4 a0, const f32x4 a1) {
    const h16x2 h01 = __builtin_amdgcn_cvt_pkrtz(a0[0], a0[1]);
    const h16x2 h23 = __builtin_amdgcn_cvt_pkrtz(a0[2], a0[3]);
    const h16x2 h45 = __builtin_amdgcn_cvt_pkrtz(a1[0], a1[1]);
    const h16x2 h67 = __builtin_amdgcn_cvt_pkrtz(a1[2], a1[3]);
    f16x8 h;
    h[0]=(_Float16)h01[0]; h[1]=(_Float16)h01[1]; h[2]=(_Float16)h23[0]; h[3]=(_Float16)h23[1];
    h[4]=(_Float16)h45[0]; h[5]=(_Float16)h45[1]; h[6]=(_Float16)h67[0]; h[7]=(_Float16)h67[1];
    return h;
}

// ---- kernel 1: means fp32 -> f16 (RN), zero-padded to NCPAD rows.  x is no
// longer converted (fused into the GEMM) -> ~12 MB traffic, ~3 us. ----------
__global__ __launch_bounds__(256)
void cvt_m_kernel(const float* __restrict__ src, _Float16* __restrict__ hi)
{
    const int i = blockIdx.x * 256 + threadIdx.x;
    const int row = (i * 4) >> 11;
    float4 v = make_float4(0.f, 0.f, 0.f, 0.f);
    if (row < NC) v = ((const float4*)src)[i];
    f16x4 h;
    h[0] = (_Float16)v.x; h[1] = (_Float16)v.y;
    h[2] = (_Float16)v.z; h[3] = (_Float16)v.w;
    ((f16x4*)hi)[i] = h;
}

// ============================================================================
// kernel 2: 256x256 f16 MFMA GEMM, ONE barrier per K-tile, fused A-convert.
//
// r5 post-mortem: gemm ~74us; cvt's x round-trip (~30us) is pure waste.  This
// round: A is staged from fp32 x in-kernel (global->reg, cvt_pkrtz, swizzled
// ds_write_b128) — cvt kernel shrinks to means-only.  B stays global_load_lds.
//
// Sync simplification: ALL staging in tile t (A reg-writes AND B gl_lds)
// targets the [nxt = par^1] buffer half.  Every [nxt] region's last readers
// are tile t-1's ds_reads, which each wave lgkm-retired before its own MFMAs,
// which precede t-1's end barrier — so after that barrier the whole [nxt]
// half is dead.  => no mid-tile barrier needed; ONE barrier per tile.
// Depth-1 prefetch suffices: tile time ~5000 cyc >> ~900 cyc HBM latency.
//
// Residency proof for tile t+1's operands at t's end barrier:
//  - A: compiler inserts vmcnt waits before each cvt (data dep) => A loads
//    retired; lgkmcnt(0) in the end asm retires the ds_writes.
//  - B: u0/u1 gl_lds issued BEFORE the A kk1 loads; vmcnt retirement is
//    in-order, so the compiler's A-kk1 wait also retires u0/u1.  The explicit
//    vmcnt(0) is a free (already-satisfied) hard guarantee.
// Tail: stage source K-tile CLAMPED to 31; clamped stages land in [nxt]
// regions never read again.
// Fragment/epilogue/swizzle layouts identical to the r1-r5-verified kernels
// (reg-staged A writes POSITION p = group ^ ((row>>1)&3), the same involution
// the gl_lds path realized via pre-swizzled source addresses).
// ============================================================================
__device__ __forceinline__ void stage_unitB(const _Float16* __restrict__ src,
                                            size_t g0, _Float16* dstbase,
                                            int srcT, int kkh, int tid)
{
#pragma unroll
    for (int q = 0; q < 2; ++q) {
        const int slot = q * 512 + tid;          // 0..1023 (16B chunks)
        const int row  = slot >> 2;              // 0..255
        const int g    = (slot & 3) ^ ((row >> 1) & 3);
        gl_lds16_h(src + ((g0 + (size_t)row) << 11) + srcT * 64 + kkh * 32 + g * 8,
                   dstbase + (size_t)(q * 512 + ((tid >> 6) << 6)) * 8);
    }
}

__global__ __launch_bounds__(512, 2)
void gemm256_kernel(const float* __restrict__ x,
                    const _Float16* __restrict__ mhi,
                    _Float16* __restrict__ sc)
{
    __shared__ _Float16 sA[2][2][256 * 32];   // [par][kk] 64 KB
    __shared__ _Float16 sB[2][2][256 * 32];   // 64 KB

    const int tid  = threadIdx.x;
    const int lane = tid & 63;
    const int w    = tid >> 6;           // 0..7
    const int wm   = w >> 2;             // 0..1 (M half)
    const int wn   = w & 3;              // 0..3 (N quarter)
    const int quad = lane >> 4, l16 = lane & 15;

    // XCD-bijective swizzle: grid (4,64) -> 256 blocks, 32 per XCD.
    const int orig = blockIdx.x + (blockIdx.y << 2);
    const int nid  = ((orig & 7) << 5) + (orig >> 3);
    const size_t gm0 = (size_t)(nid >> 2) * 256;   // sample rows
    const size_t gn0 = (size_t)(nid & 3) * 256;    // class cols

    // A reg-staging geometry: thread -> (row, 16-float segment)
    const int arow = tid >> 1;                    // 0..255
    const int aseg = tid & 1;                     // 0..1
    const int as   = (arow >> 1) & 3;
    const int ap0  = (aseg * 2)     ^ as;         // LDS group positions
    const int ap1  = (aseg * 2 + 1) ^ as;
    const float* xA = x + ((gm0 + (size_t)arow) << 11) + aseg * 16;

    f32x4 acc[8][4] = {};

    // ---- prologue: tile 0 resident ----
    stage_unitB(mhi, gn0, &sB[0][0][0], 0, 0, tid);
    stage_unitB(mhi, gn0, &sB[0][1][0], 0, 1, tid);
    {
        f32x4 v0[4], v1[4];
#pragma unroll
        for (int q = 0; q < 4; ++q) v0[q] = *(const f32x4*)(xA + q * 4);
#pragma unroll
        for (int q = 0; q < 4; ++q) v1[q] = *(const f32x4*)(xA + 32 + q * 4);
        const f16x8 h00 = cvt8(v0[0], v0[1]), h01 = cvt8(v0[2], v0[3]);
        const f16x8 h10 = cvt8(v1[0], v1[1]), h11 = cvt8(v1[2], v1[3]);
        *(f16x8*)&sA[0][0][arow * 32 + ap0 * 8] = h00;
        *(f16x8*)&sA[0][0][arow * 32 + ap1 * 8] = h01;
        *(f16x8*)&sA[0][1][arow * 32 + ap0 * 8] = h10;
        *(f16x8*)&sA[0][1][arow * 32 + ap1 * 8] = h11;
    }
    asm volatile("s_waitcnt vmcnt(0) lgkmcnt(0)" ::: "memory");
    __builtin_amdgcn_s_barrier();

    for (int kt = 0; kt < 32; ++kt) {
        const int par = kt & 1, nxt = par ^ 1;
        const int srcT = (kt + 1 < 32) ? kt + 1 : 31;   // clamp: dead-region safe
        const float* xT = xA + srcT * 64;

        // ---- cluster 1 (kk0): frag reads + ALL B staging + A kk0 loads ----
        f16x8 a0[4], a1[4], b0[4];
#pragma unroll
        for (int i = 0; i < 4; ++i) {
            const int r0 = wm * 128 + i * 16 + l16;
            const int r1 = r0 + 64;
            a0[i] = *(const f16x8*)&sA[par][0][r0 * 32 + (quad ^ ((r0 >> 1) & 3)) * 8];
            a1[i] = *(const f16x8*)&sA[par][0][r1 * 32 + (quad ^ ((r1 >> 1) & 3)) * 8];
        }
#pragma unroll
        for (int j = 0; j < 4; ++j) {
            const int br = wn * 64 + j * 16 + l16;
            b0[j] = *(const f16x8*)&sB[par][0][br * 32 + (quad ^ ((br >> 1) & 3)) * 8];
        }
        stage_unitB(mhi, gn0, &sB[nxt][0][0], srcT, 0, tid);
        stage_unitB(mhi, gn0, &sB[nxt][1][0], srcT, 1, tid);
        f32x4 av0[4];
#pragma unroll
        for (int q = 0; q < 4; ++q) av0[q] = *(const f32x4*)(xT + q * 4);
        __builtin_amdgcn_sched_barrier(0);
        __builtin_amdgcn_s_setprio(1);
#pragma unroll
        for (int i = 0; i < 4; ++i)
#pragma unroll
            for (int j = 0; j < 4; ++j)
                acc[i][j] = __builtin_amdgcn_mfma_f32_16x16x32_f16(a0[i], b0[j], acc[i][j], 0, 0, 0);
#pragma unroll
        for (int i = 0; i < 4; ++i)
#pragma unroll
            for (int j = 0; j < 4; ++j)
                acc[4 + i][j] = __builtin_amdgcn_mfma_f32_16x16x32_f16(a1[i], b0[j], acc[4 + i][j], 0, 0, 0);
        __builtin_amdgcn_s_setprio(0);

        // ---- cluster 2 (kk1): frag reads + A kk0 cvt/write + A kk1 loads ----
        f16x8 c0[4], c1[4], b1[4];
#pragma unroll
        for (int i = 0; i < 4; ++i) {
            const int r0 = wm * 128 + i * 16 + l16;
            const int r1 = r0 + 64;
            c0[i] = *(const f16x8*)&sA[par][1][r0 * 32 + (quad ^ ((r0 >> 1) & 3)) * 8];
            c1[i] = *(const f16x8*)&sA[par][1][r1 * 32 + (quad ^ ((r1 >> 1) & 3)) * 8];
        }
#pragma unroll
        for (int j = 0; j < 4; ++j) {
            const int br = wn * 64 + j * 16 + l16;
            b1[j] = *(const f16x8*)&sB[par][1][br * 32 + (quad ^ ((br >> 1) & 3)) * 8];
        }
        {   // A kk0 -> LDS[nxt][0] (region dead since t-1's end barrier)
            const f16x8 h0 = cvt8(av0[0], av0[1]), h1 = cvt8(av0[2], av0[3]);
            *(f16x8*)&sA[nxt][0][arow * 32 + ap0 * 8] = h0;
            *(f16x8*)&sA[nxt][0][arow * 32 + ap1 * 8] = h1;
        }
        f32x4 av1[4];
#pragma unroll
        for (int q = 0; q < 4; ++q) av1[q] = *(const f32x4*)(xT + 32 + q * 4);
        __builtin_amdgcn_sched_barrier(0);
        __builtin_amdgcn_s_setprio(1);
#pragma unroll
        for (int i = 0; i < 4; ++i)
#pragma unroll
            for (int j = 0; j < 4; ++j)
                acc[i][j] = __builtin_amdgcn_mfma_f32_16x16x32_f16(c0[i], b1[j], acc[i][j], 0, 0, 0);
#pragma unroll
        for (int i = 0; i < 4; ++i)
#pragma unroll
            for (int j = 0; j < 4; ++j)
                acc[4 + i][j] = __builtin_amdgcn_mfma_f32_16x16x32_f16(c1[i], b1[j], acc[4 + i][j], 0, 0, 0);
        __builtin_amdgcn_s_setprio(0);
        {   // A kk1 -> LDS[nxt][1] (dead since t-1's end barrier)
            const f16x8 h0 = cvt8(av1[0], av1[1]), h1 = cvt8(av1[2], av1[3]);
            *(f16x8*)&sA[nxt][1][arow * 32 + ap0 * 8] = h0;
            *(f16x8*)&sA[nxt][1][arow * 32 + ap1 * 8] = h1;
        }
        asm volatile("s_waitcnt vmcnt(0) lgkmcnt(0)" ::: "memory");
        __builtin_amdgcn_s_barrier();   // the ONLY barrier: opens tile t+1
    }

    // epilogue: C/D layout col=l16+j*16, row=quad*4+r (verified r1-r5)
#pragma unroll
    for (int m = 0; m < 8; ++m) {
        const size_t row0 = gm0 + wm * 128 + m * 16 + quad * 4;
#pragma unroll
        for (int j = 0; j < 4; ++j) {
            const size_t col = gn0 + wn * 64 + j * 16 + l16;
#pragma unroll
            for (int r = 0; r < 4; ++r)
                sc[(row0 + r) * NCPAD + col] = (_Float16)acc[m][j][r];
        }
    }
}

// ---- kernel 3: refine.  One wave per row.  Single-candidate fast path (the
// DELTA bound proves the lone candidate IS the exact argmax -> no dot, no
// x-row load).  Candidate iteration is ballot-driven.  UNCHANGED. -----------
__global__ __launch_bounds__(256, 4)
void refine_kernel(const _Float16* __restrict__ sc,
                   const float* __restrict__ x,
                   const float* __restrict__ means,
                   float* __restrict__ out)
{
    const int lane = threadIdx.x & 63;
    const int row  = blockIdx.x * 4 + (threadIdx.x >> 6);

    // 16 approx scores per lane (whole 1024-wide row per wave)
    const f16x8* srow = (const f16x8*)(sc + (size_t)row * NCPAD + lane * 16);
    const f16x8 s0 = srow[0], s1 = srow[1];
    float v[16];
#pragma unroll
    for (int e = 0; e < 8; ++e) { v[e] = (float)s0[e]; v[8 + e] = (float)s1[e]; }

    float mx = -INFINITY;
#pragma unroll
    for (int e = 0; e < 16; ++e) {
        const int c = lane * 16 + e;
        if (c < NC && v[e] > mx) mx = v[e];
    }
#pragma unroll
    for (int off = 1; off < 64; off <<= 1) {
        const float o = __shfl_xor(mx, off);
        if (o > mx) mx = o;
    }
    const float T = mx - DELTA;

    unsigned cm = 0;
#pragma unroll
    for (int e = 0; e < 16; ++e) {
        const int c = lane * 16 + e;
        if (c < NC && v[e] >= T) cm |= (1u << e);
    }

    const unsigned long long bl = __ballot(cm != 0u);
    const int first  = (int)__builtin_ctzll(bl);
    const unsigned cmf = (unsigned)__shfl((int)cm, first);

    int bc;
    if (__builtin_popcountll(bl) == 1 && __builtin_popcount(cmf) == 1) {
        bc = first * 16 + __builtin_ctz(cmf);
    } else {
        // slow path: preload x row (8 KB / 64 lanes = 32 fp32 per lane)
        const float* xrow = x + ((size_t)row << 11);
        f32x4 xr[8];
#pragma unroll
        for (int it = 0; it < 8; ++it)
            xr[it] = *(const f32x4*)(xrow + it * 256 + lane * 4);

        float bv = -INFINITY;
        bc = 0x7fffffff;
        unsigned long long pend = bl;
        while (pend) {
            const int src = (int)__builtin_ctzll(pend);
            pend &= pend - 1;
            unsigned cms = (unsigned)__shfl((int)cm, src);
            while (cms) {
                const int c = src * 16 + __builtin_ctz(cms);
                cms &= cms - 1;

                // exact fp32 dot(x[row], means[c]) — deterministic reduce order
                const float* mrow = means + ((size_t)c << 11);
                float part = 0.f;
#pragma unroll
                for (int it = 0; it < 8; ++it) {
                    const f32x4 mv = *(const f32x4*)(mrow + it * 256 + lane * 4);
                    part = fmaf(xr[it][0], mv[0], part);
                    part = fmaf(xr[it][1], mv[1], part);
                    part = fmaf(xr[it][2], mv[2], part);
                    part = fmaf(xr[it][3], mv[3], part);
                }
                float s = part;
#pragma unroll
                for (int off = 1; off < 64; off <<= 1) s += __shfl_xor(s, off);

                if (s > bv || (s == bv && c < bc)) { bv = s; bc = c; }
            }
        }
    }

    float4* orow = (float4*)(out + (size_t)row * NC);
#pragma unroll
    for (int i = 0; i < 4; ++i) {
        const int idx = lane + i * 64;
        if (idx < NC / 4) {
            const int cb = idx * 4;
            float4 ov;
            ov.x = (cb     == bc) ? 1.f : 0.f;
            ov.y = (cb + 1 == bc) ? 1.f : 0.f;
            ov.z = (cb + 2 == bc) ? 1.f : 0.f;
            ov.w = (cb + 3 == bc) ? 1.f : 0.f;
            orow[idx] = ov;
        }
    }
}

// ===========================================================================
// Fallback: round-1 fp32 LDS-tiled kernel (correct, ~1.9 ms) if ws too small.
// ===========================================================================
#define MS 64
#define CS 256
#define KT 32
#define NCHUNK 4

__global__ __launch_bounds__(256, 1)
void nnc_fp32_kernel(const float* __restrict__ x,
                     const float* __restrict__ means,
                     float* __restrict__ out)
{
    __shared__ float xs[MS * KT];
    __shared__ float msh[CS * KT];
    __shared__ float rbest[MS * 33];
    __shared__ int   ridx[MS * 33];
    __shared__ int   widx[MS];

    const int tid = threadIdx.x;
    const int tx  = tid & 31;
    const int ty  = tid >> 5;
    const int s0  = blockIdx.x * MS;
    const int m0  = ty * 8;
    const int cL  = tx * 8;

    float best[8];
    int   bidx[8];
#pragma unroll
    for (int i = 0; i < 8; ++i) { best[i] = -INFINITY; bidx[i] = 0; }

    const int kslot = tid & 7;
    const int rrow  = tid >> 3;

    for (int chunk = 0; chunk < NCHUNK; ++chunk) {
        const int c0 = chunk * CS;
        float acc[8][8];
#pragma unroll
        for (int i = 0; i < 8; ++i)
#pragma unroll
            for (int j = 0; j < 8; ++j) acc[i][j] = 0.0f;

        for (int k0 = 0; k0 < ND; k0 += KT) {
#pragma unroll
            for (int r = 0; r < 2; ++r) {
                const int m = rrow + r * 32;
                const float4 v = *(const float4*)(x + (size_t)(s0 + m) * ND + k0 + kslot * 4);
                *(float4*)(xs + m * KT + kslot * 4) = v;
            }
#pragma unroll
            for (int r = 0; r < 8; ++r) {
                const int c  = rrow + r * 32;
                const int cg = c0 + c;
                float4 v = make_float4(0.f, 0.f, 0.f, 0.f);
                if (cg < NC) v = *(const float4*)(means + (size_t)cg * ND + k0 + kslot * 4);
                const int pslot = (kslot + (c >> 3)) & 7;
                *(float4*)(msh + c * KT + pslot * 4) = v;
            }
            __syncthreads();
#pragma unroll
            for (int k4 = 0; k4 < KT / 4; ++k4) {
                float4 a[8], b[8];
                const int boff = ((k4 + tx) & 7) * 4;
#pragma unroll
                for (int i = 0; i < 8; ++i) a[i] = *(const float4*)(xs + (m0 + i) * KT + k4 * 4);
#pragma unroll
                for (int j = 0; j < 8; ++j) b[j] = *(const float4*)(msh + (cL + j) * KT + boff);
#pragma unroll
                for (int i = 0; i < 8; ++i)
#pragma unroll
                    for (int j = 0; j < 8; ++j) {
                        acc[i][j] = fmaf(a[i].x, b[j].x, acc[i][j]);
                        acc[i][j] = fmaf(a[i].y, b[j].y, acc[i][j]);
                        acc[i][j] = fmaf(a[i].z, b[j].z, acc[i][j]);
                        acc[i][j] = fmaf(a[i].w, b[j].w, acc[i][j]);
                    }
            }
            __syncthreads();
        }
#pragma unroll
        for (int i = 0; i < 8; ++i)
#pragma unroll
            for (int j = 0; j < 8; ++j) {
                const int c = c0 + cL + j;
                const float v = acc[i][j];
                if (c < NC && (v > best[i] || (v == best[i] && c < bidx[i]))) {
                    best[i] = v; bidx[i] = c;
                }
            }
    }
#pragma unroll
    for (int i = 0; i < 8; ++i) {
        rbest[(m0 + i) * 33 + tx] = best[i];
        ridx[(m0 + i) * 33 + tx]  = bidx[i];
    }
    __syncthreads();
    if (tid < MS) {
        float bv = rbest[tid * 33];
        int   bc = ridx[tid * 33];
        for (int t = 1; t < 32; ++t) {
            const float v = rbest[tid * 33 + t];
            const int   c = ridx[tid * 33 + t];
            if (v > bv || (v == bv && c < bc)) { bv = v; bc = c; }
        }
        widx[tid] = bc;
    }
    __syncthreads();
    if (tid < 250) {
        const int cbase = tid * 4;
        for (int m = 0; m < MS; ++m) {
            const int w = widx[m];
            float4 v;
            v.x = (cbase == w) ? 1.f : 0.f;
            v.y = (cbase + 1 == w) ? 1.f : 0.f;
            v.z = (cbase + 2 == w) ? 1.f : 0.f;
            v.w = (cbase + 3 == w) ? 1.f : 0.f;
            *(float4*)(out + (size_t)(s0 + m) * NC + cbase) = v;
        }
    }
}

extern "C" void kernel_launch(void* const* d_in, const int* in_sizes, int n_in,
                              void* d_out, int out_size, void* d_ws, size_t ws_size,
                              hipStream_t stream) {
    const float* x     = (const float*)d_in[0];
    const float* means = (const float*)d_in[1];
    float* out         = (float*)d_out;

    if (ws_size >= WS_FAST) {
        char* ws = (char*)d_ws;
        _Float16* mhi = (_Float16*)ws;                         // 4 MB
        _Float16* sc  = (_Float16*)(ws + (4ull << 20));        // 32 MB

        cvt_m_kernel<<<dim3(NCPAD * ND / 4 / 256), dim3(256), 0, stream>>>(means, mhi);
        gemm256_kernel<<<dim3(NCPAD / 256, NS / 256), dim3(512), 0, stream>>>(x, mhi, sc);
        refine_kernel<<<dim3(NS / 4), dim3(256), 0, stream>>>(sc, x, means, out);
    } else {
        nnc_fp32_kernel<<<dim3(NS / MS), dim3(256), 0, stream>>>(x, means, out);
    }
}

// Round 7
// 279.712 us; speedup vs baseline: 1.0950x; 1.0950x over previous
//
#include <hip/hip_runtime.h>
#include <math.h>

// Problem shape (fixed by the bench's setup_inputs)
#define NS 16384
#define ND 2048
#define NC 1000
#define NCPAD 1024

typedef _Float16 f16x8 __attribute__((ext_vector_type(8)));
typedef _Float16 f16x4 __attribute__((ext_vector_type(4)));
typedef __fp16   h16x2 __attribute__((ext_vector_type(2)));
typedef float f32x4  __attribute__((ext_vector_type(4)));

// Candidate window: must exceed 2*E where E bounds |approx - exact| per score.
// A is RTZ-converted in-GEMM (r0/r6-validated), B is RN.  2E ~ 1.6.
// Delta = 2.5 keeps margin.
#define DELTA 2.5f

// Fast path: mhi 4MB + sc 32MB = 36 MB
#define WS_FAST 37748736ull

__device__ __forceinline__ void gl_lds16_h(const _Float16* g, _Float16* l) {
    __builtin_amdgcn_global_load_lds(
        (const __attribute__((address_space(1))) unsigned int*)g,
        (__attribute__((address_space(3))) unsigned int*)l, 16, 0, 0);
}

// fp32x8 -> f16x8 (RTZ pack) — fused A-conversion staging
__device__ __forceinline__ f16x8 cvt8(const f32x4 a0, const f32x4 a1) {
    const h16x2 h01 = __builtin_amdgcn_cvt_pkrtz(a0[0], a0[1]);
    const h16x2 h23 = __builtin_amdgcn_cvt_pkrtz(a0[2], a0[3]);
    const h16x2 h45 = __builtin_amdgcn_cvt_pkrtz(a1[0], a1[1]);
    const h16x2 h67 = __builtin_amdgcn_cvt_pkrtz(a1[2], a1[3]);
    f16x8 h;
    h[0]=(_Float16)h01[0]; h[1]=(_Float16)h01[1]; h[2]=(_Float16)h23[0]; h[3]=(_Float16)h23[1];
    h[4]=(_Float16)h45[0]; h[5]=(_Float16)h45[1]; h[6]=(_Float16)h67[0]; h[7]=(_Float16)h67[1];
    return h;
}

// ---- kernel 1: means fp32 -> f16 (RN), zero-padded to NCPAD rows ----------
__global__ __launch_bounds__(256)
void cvt_m_kernel(const float* __restrict__ src, _Float16* __restrict__ hi)
{
    const int i = blockIdx.x * 256 + threadIdx.x;
    const int row = (i * 4) >> 11;
    float4 v = make_float4(0.f, 0.f, 0.f, 0.f);
    if (row < NC) v = ((const float4*)src)[i];
    f16x4 h;
    h[0] = (_Float16)v.x; h[1] = (_Float16)v.y;
    h[2] = (_Float16)v.z; h[3] = (_Float16)v.w;
    ((f16x4*)hi)[i] = h;
}

// ============================================================================
// kernel 2: 256x256 f16 MFMA GEMM, one barrier/tile, fused A-convert with
// CROSS-TILE register pipelining (T14 async-STAGE, depth 1 tile).
//
// r6 post-mortem: same-tile A load->cvt->write gave only ~260cyc cover vs
// ~900cyc latency AND forced vmcnt(0) drains -> 128us.  Fix: av regs loaded
// at tile t-1 are cvt'd at tile t; loads for t+2 issue after the cvt (WAR by
// program order + sched_barrier).  End-of-tile wait is COUNTED vmcnt(8).
//
// Per-tile VMEM issue order (per thread):
//   cluster1: stage B(t+1) kk0,kk1  (4 gl_lds)          [into LDS[nxt]]
//   cluster2: cvt av=A(t+1) -> 4 ds_write to LDS[nxt]   (implicit vmcnt wait
//             retires the 8 A-loads; ~3/4-tile cover)
//             issue av=A(t+2)        (8 global_load_dwordx4)
//   end: vmcnt(8) retires B(t+1) (4 oldest), leaves A(t+2) 8 in flight;
//        lgkmcnt(0) retires ds_writes; s_barrier opens tile t+1.
// Prologue: A(0) loads; B(0) stages; cvt A(0)->LDS[0] (implicit vmcnt(4));
//   A(1) loads; vmcnt(8)+lgkmcnt(0); barrier  => loop invariant holds.
// WAR: all staging targets [nxt], dead since t-1's end barrier.
// Tails: srcB/srcA clamped to 31 -> stale stages land only in dead regions;
//   final iteration's av loads are dead but un-DCE-able (rolled loop), so
//   the vmcnt ledger stays exact.
// Fragment/epilogue/swizzle layouts identical to r1-r6-verified kernels.
// ============================================================================
__device__ __forceinline__ void stage_unitB(const _Float16* __restrict__ src,
                                            size_t g0, _Float16* dstbase,
                                            int srcT, int kkh, int tid)
{
#pragma unroll
    for (int q = 0; q < 2; ++q) {
        const int slot = q * 512 + tid;          // 0..1023 (16B chunks)
        const int row  = slot >> 2;              // 0..255
        const int g    = (slot & 3) ^ ((row >> 1) & 3);
        gl_lds16_h(src + ((g0 + (size_t)row) << 11) + srcT * 64 + kkh * 32 + g * 8,
                   dstbase + (size_t)(q * 512 + ((tid >> 6) << 6)) * 8);
    }
}

__global__ __launch_bounds__(512, 2)
void gemm256_kernel(const float* __restrict__ x,
                    const _Float16* __restrict__ mhi,
                    _Float16* __restrict__ sc)
{
    __shared__ _Float16 sA[2][2][256 * 32];   // [par][kk] 64 KB
    __shared__ _Float16 sB[2][2][256 * 32];   // 64 KB

    const int tid  = threadIdx.x;
    const int lane = tid & 63;
    const int w    = tid >> 6;           // 0..7
    const int wm   = w >> 2;             // 0..1 (M half)
    const int wn   = w & 3;              // 0..3 (N quarter)
    const int quad = lane >> 4, l16 = lane & 15;

    // XCD-bijective swizzle: grid (4,64) -> 256 blocks, 32 per XCD.
    const int orig = blockIdx.x + (blockIdx.y << 2);
    const int nid  = ((orig & 7) << 5) + (orig >> 3);
    const size_t gm0 = (size_t)(nid >> 2) * 256;   // sample rows
    const size_t gn0 = (size_t)(nid & 3) * 256;    // class cols

    // A reg-staging geometry: thread -> (row, 16-float segment)
    const int arow = tid >> 1;                    // 0..255
    const int aseg = tid & 1;                     // 0..1
    const int as   = (arow >> 1) & 3;
    const int ap0  = (aseg * 2)     ^ as;         // LDS group positions
    const int ap1  = (aseg * 2 + 1) ^ as;
    const float* xA = x + ((gm0 + (size_t)arow) << 11) + aseg * 16;

    f32x4 acc[8][4] = {};
    f32x4 av[8];     // in-flight A tile: [0..3]=kk0 seg, [4..7]=kk1 seg

    // ---- prologue: establish invariant {LDS[0] resident, av=A(1) in flight,
    //      8 loads outstanding} ----
#pragma unroll
    for (int q = 0; q < 4; ++q) av[q]     = *(const f32x4*)(xA + q * 4);
#pragma unroll
    for (int q = 0; q < 4; ++q) av[4 + q] = *(const f32x4*)(xA + 32 + q * 4);
    stage_unitB(mhi, gn0, &sB[0][0][0], 0, 0, tid);
    stage_unitB(mhi, gn0, &sB[0][1][0], 0, 1, tid);
    {   // cvt A(0) -> LDS[0] (compiler inserts vmcnt wait for av)
        const f16x8 h00 = cvt8(av[0], av[1]), h01 = cvt8(av[2], av[3]);
        const f16x8 h10 = cvt8(av[4], av[5]), h11 = cvt8(av[6], av[7]);
        *(f16x8*)&sA[0][0][arow * 32 + ap0 * 8] = h00;
        *(f16x8*)&sA[0][0][arow * 32 + ap1 * 8] = h01;
        *(f16x8*)&sA[0][1][arow * 32 + ap0 * 8] = h10;
        *(f16x8*)&sA[0][1][arow * 32 + ap1 * 8] = h11;
    }
    __builtin_amdgcn_sched_barrier(0);
    {   // issue av = A(1)
        const float* xT1 = xA + 64;
#pragma unroll
        for (int q = 0; q < 4; ++q) av[q]     = *(const f32x4*)(xT1 + q * 4);
#pragma unroll
        for (int q = 0; q < 4; ++q) av[4 + q] = *(const f32x4*)(xT1 + 32 + q * 4);
    }
    asm volatile("s_waitcnt vmcnt(8) lgkmcnt(0)" ::: "memory");
    __builtin_amdgcn_s_barrier();

    for (int kt = 0; kt < 32; ++kt) {
        const int par = kt & 1, nxt = par ^ 1;
        const int srcB = (kt + 1 < 32) ? kt + 1 : 31;   // clamp: dead-region safe
        const int srcA = (kt + 2 < 32) ? kt + 2 : 31;

        // ---- cluster 1 (kk0): frag reads + B(t+1) staging + 32 MFMAs ----
        f16x8 a0[4], a1[4], b0[4];
#pragma unroll
        for (int i = 0; i < 4; ++i) {
            const int r0 = wm * 128 + i * 16 + l16;
            const int r1 = r0 + 64;
            a0[i] = *(const f16x8*)&sA[par][0][r0 * 32 + (quad ^ ((r0 >> 1) & 3)) * 8];
            a1[i] = *(const f16x8*)&sA[par][0][r1 * 32 + (quad ^ ((r1 >> 1) & 3)) * 8];
        }
#pragma unroll
        for (int j = 0; j < 4; ++j) {
            const int br = wn * 64 + j * 16 + l16;
            b0[j] = *(const f16x8*)&sB[par][0][br * 32 + (quad ^ ((br >> 1) & 3)) * 8];
        }
        stage_unitB(mhi, gn0, &sB[nxt][0][0], srcB, 0, tid);
        stage_unitB(mhi, gn0, &sB[nxt][1][0], srcB, 1, tid);
        __builtin_amdgcn_sched_barrier(0);
        __builtin_amdgcn_s_setprio(1);
#pragma unroll
        for (int i = 0; i < 4; ++i)
#pragma unroll
            for (int j = 0; j < 4; ++j)
                acc[i][j] = __builtin_amdgcn_mfma_f32_16x16x32_f16(a0[i], b0[j], acc[i][j], 0, 0, 0);
#pragma unroll
        for (int i = 0; i < 4; ++i)
#pragma unroll
            for (int j = 0; j < 4; ++j)
                acc[4 + i][j] = __builtin_amdgcn_mfma_f32_16x16x32_f16(a1[i], b0[j], acc[4 + i][j], 0, 0, 0);
        __builtin_amdgcn_s_setprio(0);

        // ---- cluster 2 (kk1): frag reads + cvt av->LDS[nxt] + issue A(t+2)
        //      + 32 MFMAs ----
        f16x8 c0[4], c1[4], b1[4];
#pragma unroll
        for (int i = 0; i < 4; ++i) {
            const int r0 = wm * 128 + i * 16 + l16;
            const int r1 = r0 + 64;
            c0[i] = *(const f16x8*)&sA[par][1][r0 * 32 + (quad ^ ((r0 >> 1) & 3)) * 8];
            c1[i] = *(const f16x8*)&sA[par][1][r1 * 32 + (quad ^ ((r1 >> 1) & 3)) * 8];
        }
#pragma unroll
        for (int j = 0; j < 4; ++j) {
            const int br = wn * 64 + j * 16 + l16;
            b1[j] = *(const f16x8*)&sB[par][1][br * 32 + (quad ^ ((br >> 1) & 3)) * 8];
        }
        {   // cvt av = A(t+1) (loaded at t-1; ~3/4-tile latency cover)
            const f16x8 h00 = cvt8(av[0], av[1]), h01 = cvt8(av[2], av[3]);
            const f16x8 h10 = cvt8(av[4], av[5]), h11 = cvt8(av[6], av[7]);
            *(f16x8*)&sA[nxt][0][arow * 32 + ap0 * 8] = h00;
            *(f16x8*)&sA[nxt][0][arow * 32 + ap1 * 8] = h01;
            *(f16x8*)&sA[nxt][1][arow * 32 + ap0 * 8] = h10;
            *(f16x8*)&sA[nxt][1][arow * 32 + ap1 * 8] = h11;
        }
        __builtin_amdgcn_sched_barrier(0);   // pin: loads below reuse av regs
        {   // issue av = A(t+2)
            const float* xT = xA + srcA * 64;
#pragma unroll
            for (int q = 0; q < 4; ++q) av[q]     = *(const f32x4*)(xT + q * 4);
#pragma unroll
            for (int q = 0; q < 4; ++q) av[4 + q] = *(const f32x4*)(xT + 32 + q * 4);
        }
        __builtin_amdgcn_sched_barrier(0);
        __builtin_amdgcn_s_setprio(1);
#pragma unroll
        for (int i = 0; i < 4; ++i)
#pragma unroll
            for (int j = 0; j < 4; ++j)
                acc[i][j] = __builtin_amdgcn_mfma_f32_16x16x32_f16(c0[i], b1[j], acc[i][j], 0, 0, 0);
#pragma unroll
        for (int i = 0; i < 4; ++i)
#pragma unroll
            for (int j = 0; j < 4; ++j)
                acc[4 + i][j] = __builtin_amdgcn_mfma_f32_16x16x32_f16(c1[i], b1[j], acc[4 + i][j], 0, 0, 0);
        __builtin_amdgcn_s_setprio(0);
        // counted wait: retires B(t+1) (4 oldest); A(t+2) 8 stay in flight
        asm volatile("s_waitcnt vmcnt(8) lgkmcnt(0)" ::: "memory");
        __builtin_amdgcn_s_barrier();   // the ONLY barrier: opens tile t+1
    }

    // epilogue: C/D layout col=l16+j*16, row=quad*4+r (verified r1-r6)
#pragma unroll
    for (int m = 0; m < 8; ++m) {
        const size_t row0 = gm0 + wm * 128 + m * 16 + quad * 4;
#pragma unroll
        for (int j = 0; j < 4; ++j) {
            const size_t col = gn0 + wn * 64 + j * 16 + l16;
#pragma unroll
            for (int r = 0; r < 4; ++r)
                sc[(row0 + r) * NCPAD + col] = (_Float16)acc[m][j][r];
        }
    }
}

// ---- kernel 3: refine.  One wave per row.  Single-candidate fast path (the
// DELTA bound proves the lone candidate IS the exact argmax -> no dot, no
// x-row load).  Candidate iteration is ballot-driven.  UNCHANGED. -----------
__global__ __launch_bounds__(256, 4)
void refine_kernel(const _Float16* __restrict__ sc,
                   const float* __restrict__ x,
                   const float* __restrict__ means,
                   float* __restrict__ out)
{
    const int lane = threadIdx.x & 63;
    const int row  = blockIdx.x * 4 + (threadIdx.x >> 6);

    // 16 approx scores per lane (whole 1024-wide row per wave)
    const f16x8* srow = (const f16x8*)(sc + (size_t)row * NCPAD + lane * 16);
    const f16x8 s0 = srow[0], s1 = srow[1];
    float v[16];
#pragma unroll
    for (int e = 0; e < 8; ++e) { v[e] = (float)s0[e]; v[8 + e] = (float)s1[e]; }

    float mx = -INFINITY;
#pragma unroll
    for (int e = 0; e < 16; ++e) {
        const int c = lane * 16 + e;
        if (c < NC && v[e] > mx) mx = v[e];
    }
#pragma unroll
    for (int off = 1; off < 64; off <<= 1) {
        const float o = __shfl_xor(mx, off);
        if (o > mx) mx = o;
    }
    const float T = mx - DELTA;

    unsigned cm = 0;
#pragma unroll
    for (int e = 0; e < 16; ++e) {
        const int c = lane * 16 + e;
        if (c < NC && v[e] >= T) cm |= (1u << e);
    }

    const unsigned long long bl = __ballot(cm != 0u);
    const int first  = (int)__builtin_ctzll(bl);
    const unsigned cmf = (unsigned)__shfl((int)cm, first);

    int bc;
    if (__builtin_popcountll(bl) == 1 && __builtin_popcount(cmf) == 1) {
        bc = first * 16 + __builtin_ctz(cmf);
    } else {
        // slow path: preload x row (8 KB / 64 lanes = 32 fp32 per lane)
        const float* xrow = x + ((size_t)row << 11);
        f32x4 xr[8];
#pragma unroll
        for (int it = 0; it < 8; ++it)
            xr[it] = *(const f32x4*)(xrow + it * 256 + lane * 4);

        float bv = -INFINITY;
        bc = 0x7fffffff;
        unsigned long long pend = bl;
        while (pend) {
            const int src = (int)__builtin_ctzll(pend);
            pend &= pend - 1;
            unsigned cms = (unsigned)__shfl((int)cm, src);
            while (cms) {
                const int c = src * 16 + __builtin_ctz(cms);
                cms &= cms - 1;

                // exact fp32 dot(x[row], means[c]) — deterministic reduce order
                const float* mrow = means + ((size_t)c << 11);
                float part = 0.f;
#pragma unroll
                for (int it = 0; it < 8; ++it) {
                    const f32x4 mv = *(const f32x4*)(mrow + it * 256 + lane * 4);
                    part = fmaf(xr[it][0], mv[0], part);
                    part = fmaf(xr[it][1], mv[1], part);
                    part = fmaf(xr[it][2], mv[2], part);
                    part = fmaf(xr[it][3], mv[3], part);
                }
                float s = part;
#pragma unroll
                for (int off = 1; off < 64; off <<= 1) s += __shfl_xor(s, off);

                if (s > bv || (s == bv && c < bc)) { bv = s; bc = c; }
            }
        }
    }

    float4* orow = (float4*)(out + (size_t)row * NC);
#pragma unroll
    for (int i = 0; i < 4; ++i) {
        const int idx = lane + i * 64;
        if (idx < NC / 4) {
            const int cb = idx * 4;
            float4 ov;
            ov.x = (cb     == bc) ? 1.f : 0.f;
            ov.y = (cb + 1 == bc) ? 1.f : 0.f;
            ov.z = (cb + 2 == bc) ? 1.f : 0.f;
            ov.w = (cb + 3 == bc) ? 1.f : 0.f;
            orow[idx] = ov;
        }
    }
}

// ===========================================================================
// Fallback: round-1 fp32 LDS-tiled kernel (correct, ~1.9 ms) if ws too small.
// ===========================================================================
#define MS 64
#define CS 256
#define KT 32
#define NCHUNK 4

__global__ __launch_bounds__(256, 1)
void nnc_fp32_kernel(const float* __restrict__ x,
                     const float* __restrict__ means,
                     float* __restrict__ out)
{
    __shared__ float xs[MS * KT];
    __shared__ float msh[CS * KT];
    __shared__ float rbest[MS * 33];
    __shared__ int   ridx[MS * 33];
    __shared__ int   widx[MS];

    const int tid = threadIdx.x;
    const int tx  = tid & 31;
    const int ty  = tid >> 5;
    const int s0  = blockIdx.x * MS;
    const int m0  = ty * 8;
    const int cL  = tx * 8;

    float best[8];
    int   bidx[8];
#pragma unroll
    for (int i = 0; i < 8; ++i) { best[i] = -INFINITY; bidx[i] = 0; }

    const int kslot = tid & 7;
    const int rrow  = tid >> 3;

    for (int chunk = 0; chunk < NCHUNK; ++chunk) {
        const int c0 = chunk * CS;
        float acc[8][8];
#pragma unroll
        for (int i = 0; i < 8; ++i)
#pragma unroll
            for (int j = 0; j < 8; ++j) acc[i][j] = 0.0f;

        for (int k0 = 0; k0 < ND; k0 += KT) {
#pragma unroll
            for (int r = 0; r < 2; ++r) {
                const int m = rrow + r * 32;
                const float4 v = *(const float4*)(x + (size_t)(s0 + m) * ND + k0 + kslot * 4);
                *(float4*)(xs + m * KT + kslot * 4) = v;
            }
#pragma unroll
            for (int r = 0; r < 8; ++r) {
                const int c  = rrow + r * 32;
                const int cg = c0 + c;
                float4 v = make_float4(0.f, 0.f, 0.f, 0.f);
                if (cg < NC) v = *(const float4*)(means + (size_t)cg * ND + k0 + kslot * 4);
                const int pslot = (kslot + (c >> 3)) & 7;
                *(float4*)(msh + c * KT + pslot * 4) = v;
            }
            __syncthreads();
#pragma unroll
            for (int k4 = 0; k4 < KT / 4; ++k4) {
                float4 a[8], b[8];
                const int boff = ((k4 + tx) & 7) * 4;
#pragma unroll
                for (int i = 0; i < 8; ++i) a[i] = *(const float4*)(xs + (m0 + i) * KT + k4 * 4);
#pragma unroll
                for (int j = 0; j < 8; ++j) b[j] = *(const float4*)(msh + (cL + j) * KT + boff);
#pragma unroll
                for (int i = 0; i < 8; ++i)
#pragma unroll
                    for (int j = 0; j < 8; ++j) {
                        acc[i][j] = fmaf(a[i].x, b[j].x, acc[i][j]);
                        acc[i][j] = fmaf(a[i].y, b[j].y, acc[i][j]);
                        acc[i][j] = fmaf(a[i].z, b[j].z, acc[i][j]);
                        acc[i][j] = fmaf(a[i].w, b[j].w, acc[i][j]);
                    }
            }
            __syncthreads();
        }
#pragma unroll
        for (int i = 0; i < 8; ++i)
#pragma unroll
            for (int j = 0; j < 8; ++j) {
                const int c = c0 + cL + j;
                const float v = acc[i][j];
                if (c < NC && (v > best[i] || (v == best[i] && c < bidx[i]))) {
                    best[i] = v; bidx[i] = c;
                }
            }
    }
#pragma unroll
    for (int i = 0; i < 8; ++i) {
        rbest[(m0 + i) * 33 + tx] = best[i];
        ridx[(m0 + i) * 33 + tx]  = bidx[i];
    }
    __syncthreads();
    if (tid < MS) {
        float bv = rbest[tid * 33];
        int   bc = ridx[tid * 33];
        for (int t = 1; t < 32; ++t) {
            const float v = rbest[tid * 33 + t];
            const int   c = ridx[tid * 33 + t];
            if (v > bv || (v == bv && c < bc)) { bv = v; bc = c; }
        }
        widx[tid] = bc;
    }
    __syncthreads();
    if (tid < 250) {
        const int cbase = tid * 4;
        for (int m = 0; m < MS; ++m) {
            const int w = widx[m];
            float4 v;
            v.x = (cbase == w) ? 1.f : 0.f;
            v.y = (cbase + 1 == w) ? 1.f : 0.f;
            v.z = (cbase + 2 == w) ? 1.f : 0.f;
            v.w = (cbase + 3 == w) ? 1.f : 0.f;
            *(float4*)(out + (size_t)(s0 + m) * NC + cbase) = v;
        }
    }
}

extern "C" void kernel_launch(void* const* d_in, const int* in_sizes, int n_in,
                              void* d_out, int out_size, void* d_ws, size_t ws_size,
                              hipStream_t stream) {
    const float* x     = (const float*)d_in[0];
    const float* means = (const float*)d_in[1];
    float* out         = (float*)d_out;

    if (ws_size >= WS_FAST) {
        char* ws = (char*)d_ws;
        _Float16* mhi = (_Float16*)ws;                         // 4 MB
        _Float16* sc  = (_Float16*)(ws + (4ull << 20));        // 32 MB

        cvt_m_kernel<<<dim3(NCPAD * ND / 4 / 256), dim3(256), 0, stream>>>(means, mhi);
        gemm256_kernel<<<dim3(NCPAD / 256, NS / 256), dim3(512), 0, stream>>>(x, mhi, sc);
        refine_kernel<<<dim3(NS / 4), dim3(256), 0, stream>>>(sc, x, means, out);
    } else {
        nnc_fp32_kernel<<<dim3(NS / MS), dim3(256), 0, stream>>>(x, means, out);
    }
}